// Round 1
// baseline (445.578 us; speedup 1.0000x reference)
//
#include <hip/hip_runtime.h>
#include <math.h>

#define NN 200000      // nodes
#define NE 6400000     // edges
#define FIN 100        // input feature dim
#define MR 10000       // sampled rows (NN/20)
#define BSH 14         // coarse bucket shift (16384-node windows)
#define NBK 13         // ceil(NN / 16384)
#define NSB 1563       // ceil(NN / 128) sub-buckets of 128 nodes
#define EPB 4096       // edges per block in stage A/B
#define CAP1E 544768   // fixed coarse-bucket capacity = 133*4096 (mean 524288 + 29 sigma)
#define SBB 133        // stage-B blocks per coarse bucket (CAP1E/EPB)
#define CAP2E 4864     // fixed sub-bucket capacity (mean 4096, sd 64 -> +12 sigma)
#define SCAP 360448    // sampled-edge list capacity (mean 320000 + huge margin)
#define STCAP 5120     // LDS sort capacity (>= CAP2E, = 10*512 register staging)

// ---------- float <-> monotonic-uint encoding for atomic min/max ----------
static __device__ __forceinline__ unsigned enc_f(float f){
  unsigned u = __float_as_uint(f);
  return (u & 0x80000000u) ? ~u : (u | 0x80000000u);
}
static __device__ __forceinline__ float dec_f(unsigned u){
  return (u & 0x80000000u) ? __uint_as_float(u ^ 0x80000000u) : __uint_as_float(~u);
}
// ---------- fp32 <-> bf16 (round-nearest-even) ----------
static __device__ __forceinline__ unsigned short f2bf(float f){
  unsigned u = __float_as_uint(f);
  return (unsigned short)((u + 0x7fffu + ((u >> 16) & 1u)) >> 16);
}
static __device__ __forceinline__ float bf2f(unsigned short h){
  return __uint_as_float(((unsigned)h) << 16);
}

// ---------- init: seed fixed-capacity cursors, zero gacc, minmax identity ----------
__global__ void k_init(int* bcur1, int* bcur2, float* gacc, unsigned* mm, unsigned* scnt){
  int i = blockIdx.x*blockDim.x + threadIdx.x;
  if(i < NBK) bcur1[i] = i*CAP1E;
  if(i < NSB) bcur2[i] = i*CAP2E;
  if(i < 2*MR) gacc[i] = 0.f;
  if(i == 0){ mm[0] = 0xFFFFFFFFu; mm[1] = 0u; scnt[0] = 0u; }
}

// ---------- stage A: partition edges into 13 fixed-capacity buckets ----------
// pack = (dst_local14 << 18) | src   (src < 2^18)
// per-wave LDS counters cut 13-bin same-address atomic contention 4x
__global__ __launch_bounds__(256) void k_stageA(const int* __restrict__ src,
                                                const int* __restrict__ dst,
                                                int* __restrict__ bcur1,
                                                unsigned* __restrict__ bucket1){
  __shared__ unsigned stage[EPB];
  __shared__ unsigned char binOf[EPB];
  __shared__ int cnt[4][NBK];
  __shared__ int tot[NBK], bst[NBK], woff[4][NBK], gbase[NBK];
  int t = threadIdx.x;
  int w = t >> 6;
  int ebase = blockIdx.x*EPB;
  int nEdge = min(EPB, NE - ebase);
  if(t < 4*NBK) ((int*)cnt)[t] = 0;
  __syncthreads();
  unsigned pk[16]; int bb[16], rr[16];
  const int4* s4 = (const int4*)(src + ebase);
  const int4* d4 = (const int4*)(dst + ebase);
  #pragma unroll
  for(int j=0;j<4;j++){
    int q = t + j*256, eo = q*4;
    if(eo < nEdge){                     // NE and all full chunks divisible by 4
      int4 s = s4[q]; int4 d = d4[q];
      int ds[4] = {d.x,d.y,d.z,d.w}, ss[4] = {s.x,s.y,s.z,s.w};
      #pragma unroll
      for(int k=0;k<4;k++){
        int b = ds[k]>>BSH;
        pk[j*4+k] = ((unsigned)(ds[k] & 16383) << 18) | (unsigned)ss[k];
        bb[j*4+k] = b;
        rr[j*4+k] = atomicAdd(&cnt[w][b], 1);
      }
    } else {
      rr[j*4+0]=rr[j*4+1]=rr[j*4+2]=rr[j*4+3] = -1;
    }
  }
  __syncthreads();
  if(t < NBK){
    int s = 0;
    #pragma unroll
    for(int wv=0; wv<4; wv++){ woff[wv][t] = s; s += cnt[wv][t]; }
    tot[t] = s;
  }
  __syncthreads();
  if(t == 0){
    int run = 0;
    #pragma unroll
    for(int b=0;b<NBK;b++){ bst[b] = run; run += tot[b]; }
  }
  __syncthreads();
  if(t < NBK && tot[t]) gbase[t] = atomicAdd(&bcur1[t], tot[t]);
  #pragma unroll
  for(int j=0;j<16;j++){
    if(rr[j] >= 0){
      int b = bb[j];
      int p = bst[b] + woff[w][b] + rr[j];
      stage[p] = pk[j]; binOf[p] = (unsigned char)b;
    }
  }
  __syncthreads();
  for(int k=t; k<nEdge; k+=256){
    int b = binOf[k];
    bucket1[gbase[b] + (k - bst[b])] = stage[k];   // coalesced ~1.3KB runs
  }
}

// ---------- stage B: refine into 1563 fixed-capacity sub-buckets (128 nodes) ----------
// statically bucket-assigned blocks (no per-edge boundary walk); also extracts
// the dst%20==0 sampled edges into a compact side list for layer-2.
// pack2 = (dst_local7 << 18) | src ; sed pack = (dst/20 << 18) | src
__global__ __launch_bounds__(256) void k_stageB(const unsigned* __restrict__ bucket1,
                                                const int* __restrict__ bcur1,
                                                int* __restrict__ bcur2,
                                                unsigned* __restrict__ bucket2,
                                                unsigned* __restrict__ sed,
                                                unsigned* __restrict__ scnt){
  __shared__ unsigned stage[EPB];
  __shared__ unsigned char binOf[EPB];
  __shared__ int cnt[128], bst[128], gbase[128];
  __shared__ unsigned sbuf[384];
  __shared__ int slds, sgbase;
  int t = threadIdx.x;
  int b = blockIdx.x / SBB;
  int chunk = blockIdx.x % SBB;
  int cntb = bcur1[b] - b*CAP1E;          // actual edges in this coarse bucket
  int el = chunk*EPB;
  int nEdge = min(EPB, cntb - el);
  if(nEdge <= 0) return;                  // block-uniform early exit
  if(t < 128) cnt[t] = 0;
  if(t == 0) slds = 0;
  __syncthreads();
  int t20 = (20 - (4*b) % 20) % 20;       // dl14 % 20 == t20  <=>  dst % 20 == 0
  unsigned pk2[16]; int ln[16], rr[16];
  const uint4* e4 = (const uint4*)(bucket1 + (size_t)b*CAP1E + el);
  #pragma unroll
  for(int j=0;j<4;j++){
    int q = t + j*256, eo = q*4;
    uint4 e = make_uint4(0,0,0,0);
    if(eo < nEdge) e = e4[q];             // may over-read into in-bounds slack; guarded per-elem
    unsigned ev[4] = {e.x, e.y, e.z, e.w};
    #pragma unroll
    for(int k=0;k<4;k++){
      int idx = j*4+k;
      if(eo + k < nEdge){
        unsigned p = ev[k];
        unsigned dl14 = p >> 18;
        int bin = (int)(dl14 >> 7);       // 0..127, same coarse bucket for whole block
        pk2[idx] = ((dl14 & 127u) << 18) | (p & 0x3FFFFu);
        ln[idx] = bin;
        rr[idx] = atomicAdd(&cnt[bin], 1);
        if((int)(dl14 % 20u) == t20){
          int sp = atomicAdd(&slds, 1);
          if(sp < 384){
            unsigned sidx = (unsigned)((b*16384 + (int)dl14) / 20);
            sbuf[sp] = (sidx << 18) | (p & 0x3FFFFu);
          }
        }
      } else rr[idx] = -1;
    }
  }
  __syncthreads();
  if(t == 0){
    int run = 0;
    for(int i=0;i<128;i++){ bst[i] = run; run += cnt[i]; }
    if(slds > 384) slds = 384;
    sgbase = (slds > 0) ? (int)atomicAdd(scnt, (unsigned)slds) : 0;
  }
  __syncthreads();
  if(t < 128 && cnt[t]){
    int sbg = (b<<7) + t;                 // global sub-bucket (cnt>0 => valid)
    gbase[t] = atomicAdd(&bcur2[sbg], cnt[t]);
  }
  #pragma unroll
  for(int j=0;j<16;j++){
    if(rr[j] >= 0){
      int p = bst[ln[j]] + rr[j];
      stage[p] = pk2[j]; binOf[p] = (unsigned char)ln[j];
    }
  }
  __syncthreads();
  for(int k=t; k<nEdge; k+=256){
    int bin = binOf[k];
    bucket2[gbase[bin] + (k - bst[bin])] = stage[k];   // coalesced ~128B runs
  }
  for(int k=t; k<slds; k+=256){
    int gp = sgbase + k;
    if(gp < SCAP) sed[gp] = sbuf[k];
  }
}

// ---------- per-node degree from bucket2 (LDS counts) -> dinv ----------
__global__ __launch_bounds__(256) void k_cnt(const unsigned* __restrict__ bucket2,
                                             const int* __restrict__ bcur2,
                                             float* __restrict__ dinv){
  __shared__ int c[128];
  int sb = blockIdx.x, t = threadIdx.x;
  if(t < 128) c[t] = 0;
  __syncthreads();
  int e0 = sb*CAP2E, e1 = bcur2[sb];
  for(int i=e0+t; i<e1; i+=256){
    unsigned pkv = bucket2[i];
    atomicAdd(&c[pkv>>18], 1);
  }
  __syncthreads();
  if(t < 128){
    int g = sb*128 + t;
    if(g < NN) dinv[g] = rsqrtf((float)(c[t] + 1));   // +1 self loop
  }
}

// ---------- h1b[row][c] = bf16( dinv[row] * (x @ W1)[row][c] ), 16 cols ----------
__global__ __launch_bounds__(256) void k_xw1(const float* __restrict__ x,
                                             const float* __restrict__ W1,
                                             const float* __restrict__ dinv,
                                             unsigned short* __restrict__ h1b){
  int row = blockIdx.x*256 + threadIdx.x;
  if(row >= NN) return;
  const float4* xr = (const float4*)(x + (size_t)row*FIN);
  float acc[16];
  #pragma unroll
  for(int c=0;c<16;c++) acc[c] = 0.f;
  #pragma unroll 5
  for(int kk=0;kk<25;kk++){
    float4 xv = xr[kk];
    const float* w = W1 + kk*4*16;   // uniform addresses -> scalar loads
    #pragma unroll
    for(int c=0;c<16;c++){
      acc[c] += xv.x*w[c] + xv.y*w[16+c] + xv.z*w[32+c] + xv.w*w[48+c];
    }
  }
  float dv = dinv[row];
  unsigned p[8];
  #pragma unroll
  for(int c=0;c<8;c++){
    p[c] = (unsigned)f2bf(acc[2*c]*dv) | ((unsigned)f2bf(acc[2*c+1]*dv) << 16);
  }
  uint4* o = (uint4*)(h1b + (size_t)row*16);
  o[0] = make_uint4(p[0],p[1],p[2],p[3]);
  o[1] = make_uint4(p[4],p[5],p[6],p[7]);
}

// ---------- fused layer-1 aggregation per sub-bucket + bias/relu/@W2 ----------
// Register-staged counting sort (single global read of bucket2), then per-node
// register accumulation with 8-lane groups loading 4B (2 bf16 features) per lane.
__global__ __launch_bounds__(512) void k_aggfused(const unsigned* __restrict__ bucket2,
                                                  const int* __restrict__ bcur2,
                                                  const float* __restrict__ dinv,
                                                  const unsigned short* __restrict__ h1b,
                                                  const float* __restrict__ b1,
                                                  const float* __restrict__ W2,
                                                  float* __restrict__ h2s){
  __shared__ unsigned srt[STCAP];          // sorted src ids (20 KB)
  __shared__ int cnt[128], coff[129], cur[128];
  __shared__ int wsum0;
  int t = threadIdx.x, sb = blockIdx.x;
  int e0 = sb*CAP2E, e1 = bcur2[sb];
  int n  = e1 - e0;
  bool ok = (n <= STCAP);                  // block-uniform; always true by sizing
  if(t < 128) cnt[t] = 0;
  __syncthreads();

  if(ok){
    // pass 1: load edges to registers + per-node histogram (single global read)
    unsigned er[10];
    #pragma unroll
    for(int k=0;k<10;k++){
      int i = e0 + t + k*512;
      if(i < e1){
        unsigned p = bucket2[i];
        er[k] = p;
        atomicAdd(&cnt[p>>18], 1);
      } else er[k] = 0xFFFFFFFFu;          // sentinel (real packs < 2^25)
    }
    __syncthreads();
    // scan 128 bins: wave-level shfl scan
    int v = (t<128) ? cnt[t] : 0;
    int s = v;
    #pragma unroll
    for(int o=1;o<64;o<<=1){
      int u = __shfl_up(s, o, 64);
      if((t&63) >= o) s += u;
    }
    if(t == 63) wsum0 = s;
    __syncthreads();
    if(t < 128){
      int ex = s - v + ((t>=64) ? wsum0 : 0);
      coff[t] = ex; cur[t] = ex;
    }
    if(t == 0) coff[128] = n;
    __syncthreads();
    // pass 2: scatter from registers into LDS
    #pragma unroll
    for(int k=0;k<10;k++){
      if(er[k] != 0xFFFFFFFFu){
        int p = atomicAdd(&cur[er[k]>>18], 1);
        srt[p] = er[k] & 0x3FFFFu;
      }
    }
    __syncthreads();
    // per-node register accumulation: 64 groups of 8 lanes, 4B/lane gathers
    int grp = t>>3, f2 = t&7;              // lane covers features {2*f2, 2*f2+1}
    const unsigned* h1u = (const unsigned*)h1b;
    for(int nd=grp; nd<128; nd+=64){
      int g = sb*128 + nd;
      if(g >= NN) continue;
      int s0 = coff[nd], s1 = coff[nd+1];
      unsigned su = h1u[(size_t)g*8 + f2];         // self loop
      float acc0 = bf2f((unsigned short)su);
      float acc1 = bf2f((unsigned short)(su>>16));
      int j = s0;
      for(; j+4 <= s1; j+=4){
        unsigned a0=srt[j], a1=srt[j+1], a2=srt[j+2], a3=srt[j+3];
        unsigned u0 = h1u[a0*8+f2], u1 = h1u[a1*8+f2];
        unsigned u2 = h1u[a2*8+f2], u3 = h1u[a3*8+f2];
        acc0 += (bf2f((unsigned short)u0) + bf2f((unsigned short)u1))
              + (bf2f((unsigned short)u2) + bf2f((unsigned short)u3));
        acc1 += (bf2f((unsigned short)(u0>>16)) + bf2f((unsigned short)(u1>>16)))
              + (bf2f((unsigned short)(u2>>16)) + bf2f((unsigned short)(u3>>16)));
      }
      for(; j<s1; j++){
        unsigned u = h1u[srt[j]*8+f2];
        acc0 += bf2f((unsigned short)u);
        acc1 += bf2f((unsigned short)(u>>16));
      }
      float dvd = dinv[g];
      float r0 = fmaxf(dvd*acc0 + b1[2*f2],   0.f);
      float r1 = fmaxf(dvd*acc1 + b1[2*f2+1], 0.f);
      float p0 = r0*W2[(2*f2)*2+0] + r1*W2[(2*f2+1)*2+0];
      float p1 = r0*W2[(2*f2)*2+1] + r1*W2[(2*f2+1)*2+1];
      #pragma unroll
      for(int o=4;o>0;o>>=1){
        p0 += __shfl_xor(p0, o, 8);
        p1 += __shfl_xor(p1, o, 8);
      }
      if(f2 == 0){
        h2s[g*2+0] = dvd * p0;     // pre-fold dinv[d] for layer-2 gathers
        h2s[g*2+1] = dvd * p1;
      }
    }
  } else {
    // fallback (n > STCAP, unreachable with CAP2E sizing): LDS-atomic path
    float* accf = (float*)srt;               // reuse srt as acc[128][16]
    for(int i=t; i<2048; i+=512) accf[i] = 0.f;
    __syncthreads();
    int grp = t>>4, f = t&15;
    for(int i=e0+grp; i<e1; i+=32){
      unsigned pkv = bucket2[i];
      atomicAdd(&accf[(pkv>>18)*16 + f], bf2f(h1b[(size_t)(pkv & 0x3FFFFu)*16 + f]));
    }
    __syncthreads();
    for(int nd=grp; nd<128; nd+=32){
      int g = sb*128 + nd;
      if(g >= NN) continue;
      float dvd = dinv[g];
      float acc = accf[nd*16 + f] + bf2f(h1b[(size_t)g*16 + f]);
      float r = fmaxf(dvd*acc + b1[f], 0.f);
      float p0 = r * W2[f*2+0];
      float p1 = r * W2[f*2+1];
      #pragma unroll
      for(int o=8;o>0;o>>=1){
        p0 += __shfl_xor(p0, o, 16);
        p1 += __shfl_xor(p1, o, 16);
      }
      if(f == 0){
        h2s[g*2+0] = dvd * p0;
        h2s[g*2+1] = dvd * p1;
      }
    }
  }
}

// ---------- layer-2: accumulate only the pre-extracted sampled edges ----------
__global__ __launch_bounds__(256) void k_agg2s(const unsigned* __restrict__ sed,
                                               const unsigned* __restrict__ scnt,
                                               const float* __restrict__ h2s,
                                               float* __restrict__ gacc){
  int total = (int)scnt[0];
  if(total > SCAP) total = SCAP;
  const float2* h2v = (const float2*)h2s;
  for(int i = blockIdx.x*256 + threadIdx.x; i < total; i += gridDim.x*256){
    unsigned p = sed[i];
    int idx = (int)(p >> 18);
    int srcn = (int)(p & 0x3FFFFu);
    float2 v = h2v[srcn];
    atomicAdd(&gacc[idx*2+0], v.x);
    atomicAdd(&gacc[idx*2+1], v.y);
  }
}

// ---------- post: self loop + bias + log_softmax + fused minmax ----------
__global__ __launch_bounds__(256) void k_post(const float* __restrict__ gacc,
                                              const float* __restrict__ h2s,
                                              const float* __restrict__ dinv,
                                              const float* __restrict__ b2,
                                              const float* __restrict__ t1,
                                              const float* __restrict__ t2,
                                              const float* __restrict__ t3,
                                              float* __restrict__ gout,
                                              unsigned* __restrict__ mm){
  int i = blockIdx.x*256 + threadIdx.x;
  float lo = 3.4e38f, hi = -3.4e38f;
  if(i < MR){
    int g = i*20;
    float dvd = dinv[g];
    float o0 = dvd*(gacc[i*2+0] + h2s[g*2+0]) + b2[0];
    float o1 = dvd*(gacc[i*2+1] + h2s[g*2+1]) + b2[1];
    float m = fmaxf(o0, o1);
    float lse = m + logf(expf(o0-m) + expf(o1-m));
    float g0 = o0 - lse, g1 = o1 - lse;
    gout[i*2+0] = g0; gout[i*2+1] = g1;
    float a = t1[i], bb = t2[i], c = t3[i];
    lo = fminf(fminf(a,bb), fminf(c, fminf(g0,g1)));
    hi = fmaxf(fmaxf(a,bb), fmaxf(c, fmaxf(g0,g1)));
  }
  #pragma unroll
  for(int o=32;o>0;o>>=1){
    lo = fminf(lo, __shfl_xor(lo, o, 64));
    hi = fmaxf(hi, __shfl_xor(hi, o, 64));
  }
  __shared__ float slo[4], shi[4];
  int w = threadIdx.x >> 6, l = threadIdx.x & 63;
  if(l == 0){ slo[w] = lo; shi[w] = hi; }
  __syncthreads();
  if(threadIdx.x == 0){
    for(int j=1;j<4;j++){ lo = fminf(lo, slo[j]); hi = fmaxf(hi, shi[j]); }
    atomicMin(&mm[0], enc_f(lo));
    atomicMax(&mm[1], enc_f(hi));
  }
}

// ---------- MLP head ----------
__global__ __launch_bounds__(256) void k_mlp(const float* __restrict__ t1, const float* __restrict__ t2,
                                             const float* __restrict__ t3, const float* __restrict__ g,
                                             const unsigned* __restrict__ mm,
                                             const float* __restrict__ W1, const float* __restrict__ b1,
                                             const float* __restrict__ W2, const float* __restrict__ b2,
                                             const float* __restrict__ W3, const float* __restrict__ b3,
                                             float* __restrict__ out){
  int i = blockIdx.x*256 + threadIdx.x;
  if(i >= MR) return;
  float mn = dec_f(mm[0]), mx = dec_f(mm[1]);
  float sc = 1.f/(mx - mn);
  float in[5];
  in[0] = (t1[i]   - mn)*sc;
  in[1] = (t2[i]   - mn)*sc;
  in[2] = (t3[i]   - mn)*sc;
  in[3] = (g[2*i]  - mn)*sc;
  in[4] = (g[2*i+1]- mn)*sc;
  float a[80];
  #pragma unroll
  for(int j=0;j<80;j++){
    float s = b1[j];
    #pragma unroll
    for(int k=0;k<5;k++) s += in[k]*W1[k*80+j];
    a[j] = fmaxf(s, 0.f);
  }
  float h[10];
  #pragma unroll
  for(int j=0;j<10;j++){
    float s = b2[j];
    #pragma unroll
    for(int k=0;k<80;k++) s += a[k]*W2[k*10+j];
    h[j] = fmaxf(s, 0.f);
  }
  float o = b3[0];
  #pragma unroll
  for(int k=0;k<10;k++) o += h[k]*W3[k];
  out[i] = 1.f/(1.f + expf(-o));
}

extern "C" void kernel_launch(void* const* d_in, const int* in_sizes, int n_in,
                              void* d_out, int out_size, void* d_ws, size_t ws_size,
                              hipStream_t stream) {
  (void)in_sizes; (void)n_in; (void)out_size; (void)ws_size;
  const int*   eidx    = (const int*)  d_in[0];   // [2, NE]
  const int*   src     = eidx;
  const int*   dst     = eidx + NE;
  const float* x       = (const float*)d_in[1];   // [NN, 100]
  const float* transE  = (const float*)d_in[4];
  const float* ComplEx = (const float*)d_in[5];
  const float* path    = (const float*)d_in[6];
  const float* ghW1    = (const float*)d_in[8];
  const float* ghb1    = (const float*)d_in[9];
  const float* ghW2    = (const float*)d_in[10];
  const float* ghb2    = (const float*)d_in[11];
  const float* mW1     = (const float*)d_in[16];
  const float* mb1     = (const float*)d_in[17];
  const float* mW2     = (const float*)d_in[18];
  const float* mb2     = (const float*)d_in[19];
  const float* mW3     = (const float*)d_in[20];
  const float* mb3     = (const float*)d_in[21];
  float* out = (float*)d_out;

  // workspace carve-up (~69 MB)
  char* w = (char*)d_ws;
  size_t off = 0;
  auto alloc = [&](size_t bytes)->void*{
    void* p = w + off;
    off += (bytes + 255) & ~(size_t)255;
    return p;
  };
  unsigned* bucket1 = (unsigned*)alloc((size_t)NBK*CAP1E*4);   // 28.3 MB
  unsigned* bucket2 = (unsigned*)alloc((size_t)NSB*CAP2E*4);   // 30.4 MB
  float*    dinv    = (float*)   alloc((size_t)NN*4);
  unsigned short* h1b = (unsigned short*)alloc((size_t)NN*16*2);
  float*    h2s     = (float*)   alloc((size_t)NN*2*4);
  float*    gacc    = (float*)   alloc((size_t)MR*2*4);
  float*    gout    = (float*)   alloc((size_t)MR*2*4);
  unsigned* sed     = (unsigned*)alloc((size_t)SCAP*4);        // 1.4 MB
  int*      bcur1   = (int*)     alloc(64*4);
  int*      bcur2   = (int*)     alloc((size_t)(NSB+1)*4);
  unsigned* mm      = (unsigned*)alloc(256);
  unsigned* scnt    = (unsigned*)alloc(256);

  const int SA_BLOCKS = (NE + EPB - 1)/EPB;   // 1563
  const int SB_BLOCKS = NBK*SBB;              // 1729 (statically bucket-assigned)

  k_init    <<<(2*MR+255)/256, 256, 0, stream>>>(bcur1, bcur2, gacc, mm, scnt);
  k_stageA  <<<SA_BLOCKS, 256, 0, stream>>>(src, dst, bcur1, bucket1);
  k_stageB  <<<SB_BLOCKS, 256, 0, stream>>>(bucket1, bcur1, bcur2, bucket2, sed, scnt);
  k_cnt     <<<NSB, 256, 0, stream>>>(bucket2, bcur2, dinv);
  k_xw1     <<<(NN+255)/256, 256, 0, stream>>>(x, ghW1, dinv, h1b);
  k_aggfused<<<NSB, 512, 0, stream>>>(bucket2, bcur2, dinv, h1b, ghb1, ghW2, h2s);
  k_agg2s   <<<512, 256, 0, stream>>>(sed, scnt, h2s, gacc);
  k_post    <<<(MR+255)/256, 256, 0, stream>>>(gacc, h2s, dinv, ghb2,
                                               transE, ComplEx, path, gout, mm);
  k_mlp     <<<(MR+255)/256, 256, 0, stream>>>(transE, ComplEx, path, gout, mm,
                                               mW1, mb1, mW2, mb2, mW3, mb3, out);
}